// Round 3
// baseline (498.888 us; speedup 1.0000x reference)
//
#include <hip/hip_runtime.h>
#include <hip/hip_bf16.h>

#define N_NODES 50000
#define DIM 128
#define N_GRAPHS 64
#define E_RAW 800000
#define E_TOT 850000
#define NSLOT 1000000   // E_TOT + 3*N_NODES: exact upper bound on padded slots
#define E_CAP 1200000
#define NEG_SLOPE 0.2f
#define PAD_SENT 0xFFFF0000u   // src field = 0 (safe gather), dst field = 0xFFFF (pad)

typedef unsigned int uint;
typedef unsigned short ushort;
typedef float v2f __attribute__((ext_vector_type(2)));
typedef short bf16x8 __attribute__((ext_vector_type(8)));
typedef float f32x4 __attribute__((ext_vector_type(4)));

// Column permutation pi (storage position -> logical feature), fixed by the
// MFMA C/D fragment layout: pi(p) = (p>>3) + 32*((p>>1)&3) + 16*(p&1)
__device__ __forceinline__ int pi_pos(int p) {
    return (p >> 3) + 32 * ((p >> 1) & 3) + 16 * (p & 1);
}

__device__ __forceinline__ ushort f2bf(float f) {
    uint u = __float_as_uint(f);
    u += 0x7fffu + ((u >> 16) & 1u);      // RNE
    return (ushort)(u >> 16);
}

// ---------- init: counters + pooled only ----------
__global__ void init_kernel(int* deg, int* fillc, float* pooled) {
    int i = blockIdx.x * blockDim.x + threadIdx.x;
    if (i < N_NODES) { deg[i] = 0; fillc[i] = 0; }
    if (i < N_GRAPHS * DIM) pooled[i] = 0.f;
}

// ---------- fill csr[0..NSLOT) with pad sentinel ----------
__global__ void csr_init_kernel(uint* __restrict__ csr) {
    int i = blockIdx.x * blockDim.x + threadIdx.x;
    if (i < NSLOT / 4) ((uint4*)csr)[i] = make_uint4(PAD_SENT, PAD_SENT, PAD_SENT, PAD_SENT);
}

// ---------- layer-0 input fp32 -> bf16 (natural order) ----------
__global__ void x2bf_kernel(const float* __restrict__ x, ushort* __restrict__ xb) {
    int i = blockIdx.x * blockDim.x + threadIdx.x;
    if (i >= N_NODES * DIM / 4) return;
    float4 v = ((const float4*)x)[i];
    ushort4 o;
    o.x = f2bf(v.x); o.y = f2bf(v.y); o.z = f2bf(v.z); o.w = f2bf(v.w);
    ((ushort4*)xb)[i] = o;
}

// ---------- pack W into per-lane MFMA B-fragment layout (bf16) ----------
__global__ void wprep_kernel(const float* __restrict__ Ws, ushort* __restrict__ Wfrag) {
    int t = blockIdx.x * blockDim.x + threadIdx.x;
    if (t >= 3 * 32 * 64) return;
    int l = t >> 11;
    int rem = t & 2047;
    int chunk = rem >> 6, lane = rem & 63;
    int ks = chunk >> 3, nt = chunk & 7;
    int cc = lane & 15, gg = lane >> 4;
    const float* W = Ws + (size_t)l * DIM * DIM;
    ushort o[8];
#pragma unroll
    for (int j = 0; j < 8; ++j) {
        int kp = ks * 32 + gg * 8 + j;
        int kl = (l == 0) ? kp : pi_pos(kp);
        o[j] = f2bf(W[kl * DIM + nt * 16 + cc]);
    }
#pragma unroll
    for (int j = 0; j < 8; ++j) Wfrag[(size_t)t * 8 + j] = o[j];
}

// ---------- CSR build (dst-sorted, segments padded to multiple of 4) ----------
__global__ void count_kernel(const int* __restrict__ ei, int* __restrict__ deg) {
    int e = blockIdx.x * blockDim.x + threadIdx.x;
    if (e >= E_TOT) return;
    int dst = (e < E_RAW) ? ei[E_RAW + e] : (e - E_RAW);
    atomicAdd(&deg[dst], 1);
}

__global__ void scan1_kernel(const int* __restrict__ deg, int* __restrict__ excl,
                             int* __restrict__ blksum, int n) {
    __shared__ int lds[256];
    int t = threadIdx.x;
    int i = blockIdx.x * 256 + t;
    int v = (i < n) ? ((deg[i] + 3) & ~3) : 0;   // pad degree to multiple of 4
    lds[t] = v;
    __syncthreads();
    int incl = v;
    for (int off = 1; off < 256; off <<= 1) {
        int y = (t >= off) ? lds[t - off] : 0;
        __syncthreads();
        incl += y;
        lds[t] = incl;
        __syncthreads();
    }
    if (i < n) excl[i] = incl - v;
    if (t == 255) blksum[blockIdx.x] = incl;
}

__global__ void scan2_kernel(int* __restrict__ blksum, int* __restrict__ row_ptr, int nblk) {
    __shared__ int lds[256];
    int t = threadIdx.x;
    int v = (t < nblk) ? blksum[t] : 0;
    lds[t] = v;
    __syncthreads();
    int incl = v;
    for (int off = 1; off < 256; off <<= 1) {
        int y = (t >= off) ? lds[t - off] : 0;
        __syncthreads();
        incl += y;
        lds[t] = incl;
        __syncthreads();
    }
    if (t < nblk) blksum[t] = incl - v;
    if (t == nblk - 1) row_ptr[N_NODES] = incl;
}

__global__ void scan3_kernel(int* __restrict__ row_ptr, const int* __restrict__ blksum, int n) {
    int i = blockIdx.x * blockDim.x + threadIdx.x;
    if (i < n) row_ptr[i] += blksum[i >> 8];
}

// packed entry: src | (dst<<16). N_NODES < 65536 so both fit.
__global__ void fill_kernel(const int* __restrict__ ei, const int* __restrict__ row_ptr,
                            int* __restrict__ fillc, uint* __restrict__ csr) {
    int e = blockIdx.x * blockDim.x + threadIdx.x;
    if (e >= E_TOT) return;
    int src, dst;
    if (e < E_RAW) { src = ei[e]; dst = ei[E_RAW + e]; }
    else           { src = dst = e - E_RAW; }
    int slot = row_ptr[dst] + atomicAdd(&fillc[dst], 1);
    csr[slot] = (uint)src | ((uint)dst << 16);
}

// ---------- MFMA GEMM + fused attention dots; H packed fp8 e4m3 (pi order) ----
__global__ __launch_bounds__(256) void gemm_mfma_kernel(
    const ushort* __restrict__ Xb, const ushort* __restrict__ Wfrag,
    const float* __restrict__ asrc, const float* __restrict__ adst,
    uint* __restrict__ Hb, float* __restrict__ s1, float* __restrict__ s2, int nrows) {
    int wv = threadIdx.x >> 6;
    int lane = threadIdx.x & 63;
    int c = lane & 15, g = lane >> 4;
    int row0 = blockIdx.x * 64 + wv * 16;

    int arow = row0 + c;
    if (arow >= nrows) arow = nrows - 1;           // tail clamp (writes guarded)
    const ushort* xrow = Xb + (size_t)arow * DIM;

    f32x4 acc[8];
#pragma unroll
    for (int nt = 0; nt < 8; ++nt) acc[nt] = (f32x4)(0.f);

#pragma unroll
    for (int ks = 0; ks < 4; ++ks) {
        bf16x8 afrag = *(const bf16x8*)(xrow + ks * 32 + g * 8);
#pragma unroll
        for (int nt = 0; nt < 8; ++nt) {
            bf16x8 bfrag = *(const bf16x8*)(Wfrag + ((size_t)(ks * 8 + nt) * 64 + lane) * 8);
            acc[nt] = __builtin_amdgcn_mfma_f32_16x16x32_bf16(afrag, bfrag, acc[nt], 0, 0, 0);
        }
    }

    float a1[8], a2[8];
#pragma unroll
    for (int nt = 0; nt < 8; ++nt) { a1[nt] = asrc[c + 16 * nt]; a2[nt] = adst[c + 16 * nt]; }

#pragma unroll
    for (int r = 0; r < 4; ++r) {
        int outrow = row0 + g * 4 + r;
        bool valid = outrow < nrows;
        if (valid) {
            int w0 = __builtin_amdgcn_cvt_pk_fp8_f32(acc[0][r], acc[1][r], 0, false);
            w0     = __builtin_amdgcn_cvt_pk_fp8_f32(acc[2][r], acc[3][r], w0, true);
            int w1 = __builtin_amdgcn_cvt_pk_fp8_f32(acc[4][r], acc[5][r], 0, false);
            w1     = __builtin_amdgcn_cvt_pk_fp8_f32(acc[6][r], acc[7][r], w1, true);
            *(uint2*)&Hb[(size_t)outrow * 32 + c * 2] = make_uint2((uint)w0, (uint)w1);
        }
        float p1 = 0.f, p2 = 0.f;
#pragma unroll
        for (int nt = 0; nt < 8; ++nt) {
            p1 = fmaf(acc[nt][r], a1[nt], p1);
            p2 = fmaf(acc[nt][r], a2[nt], p2);
        }
#pragma unroll
        for (int m = 1; m < 16; m <<= 1) { p1 += __shfl_xor(p1, m); p2 += __shfl_xor(p2, m); }
        if (c == 0 && valid) { s1[outrow] = p1; s2[outrow] = p2; }
    }
}

// ---------- per-edge attention weight, computed ONCE per edge ----------
// packed csr: src = lo16, dst = hi16; pad slots (dst==0xFFFF) get w = 0.
__global__ __launch_bounds__(256) void ew_kernel(
    const uint* __restrict__ csr, const float* __restrict__ s1,
    const float* __restrict__ s2, float* __restrict__ w) {
    int i = blockIdx.x * blockDim.x + threadIdx.x;
    if (i >= NSLOT / 4) return;
    uint4 e = ((const uint4*)csr)[i];
    uint ev[4] = {e.x, e.y, e.z, e.w};
    float ov[4];
#pragma unroll
    for (int j = 0; j < 4; ++j) {
        uint dv = ev[j] >> 16;
        uint sv = ev[j] & 0xFFFFu;
        float wv = 0.f;
        if (dv != 0xFFFFu) {
            float al = s1[sv] + s2[dv];
            al = fmaxf(al, NEG_SLOPE * al);     // leaky-relu
            wv = __expf(al);
        }
        ov[j] = wv;
    }
    float4 o;
    o.x = ov[0]; o.y = ov[1]; o.z = ov[2]; o.w = ov[3];
    ((float4*)w)[i] = o;
}

// ---------- weighted gather-aggregate: one wave per FOUR dst nodes ----------
// Each dword gather covers TWO edge fp8 rows (lanes 0-31 = even edge, 32-63 =
// odd edge); each lane accumulates 4 consecutive pi-storage features 4q..4q+3.
// 4 nodes/wave (vs 8) doubles wave count for latency hiding; head loads are
// small now that edge weights are precomputed.
__global__ __launch_bounds__(256) void agg_kernel(
    const uint* __restrict__ Hb, const uint* __restrict__ csr,
    const int* __restrict__ row_ptr, const float* __restrict__ w,
    const float* __restrict__ bias,
    ushort* __restrict__ Xout, const int* __restrict__ batch,
    float* __restrict__ pooled, int pool_flag, int ngroups) {
    int gw = (blockIdx.x * blockDim.x + threadIdx.x) >> 6;
    gw = __builtin_amdgcn_readfirstlane(gw);   // wave-uniform: enable s_load paths
    if (gw >= ngroups) return;
    int lane = threadIdx.x & 63;
    int node0 = gw * 4;
    int q = lane & 31;          // dword (4-feature) index within fp8 row
    int h = lane >> 5;          // 0: even edges, 1: odd edges

    int4 rpa = *(const int4*)&row_ptr[node0];
    int rp4 = row_ptr[node0 + 4];
    int rp[5] = {rpa.x, rpa.y, rpa.z, rpa.w, rp4};

    int p0 = 4 * q + 2 * h;     // pi-storage position this lane writes (even)
    float2 b2;
    b2.x = bias[pi_pos(p0)];
    b2.y = bias[pi_pos(p0) + 16];

    int ba[4] = {0, 0, 0, 0};
    if (pool_flag) {
        int4 bq = *(const int4*)&batch[node0];
        ba[0] = bq.x; ba[1] = bq.y; ba[2] = bq.z; ba[3] = bq.w;
    }

#pragma unroll
    for (int k = 0; k < 4; ++k) {
        int beg = rp[k], end = rp[k + 1];
        float acc0 = 0.f, acc1 = 0.f, acc2 = 0.f, acc3 = 0.f, ws = 0.f;

        for (int s = beg; s < end; s += 8) {
            uint4 a = *(const uint4*)&csr[s];
            float4 wa = *(const float4*)&w[s];
            bool vb = (s + 4) < end;                     // wave-uniform
            uint4 b = vb ? *(const uint4*)&csr[s + 4]
                         : make_uint4(PAD_SENT, PAD_SENT, PAD_SENT, PAD_SENT);
            float4 wb = vb ? *(const float4*)&w[s + 4] : make_float4(0.f, 0.f, 0.f, 0.f);
            uint sn[8] = {a.x, a.y, a.z, a.w, b.x, b.y, b.z, b.w};
            float wv[8] = {wa.x, wa.y, wa.z, wa.w, wb.x, wb.y, wb.z, wb.w};
#pragma unroll
            for (int p2 = 0; p2 < 4; ++p2) {
                uint esel = h ? sn[2 * p2 + 1] : sn[2 * p2];
                float wsel = h ? wv[2 * p2 + 1] : wv[2 * p2];
                uint rsel = esel & 0xFFFFu;              // pad -> row 0 (w = 0)
                uint hv = Hb[rsel * 32u + (uint)q];
                v2f f0 = __builtin_amdgcn_cvt_pk_f32_fp8((int)hv, false);
                v2f f1 = __builtin_amdgcn_cvt_pk_f32_fp8((int)hv, true);
                acc0 = fmaf(wsel, f0.x, acc0);
                acc1 = fmaf(wsel, f0.y, acc1);
                acc2 = fmaf(wsel, f1.x, acc2);
                acc3 = fmaf(wsel, f1.y, acc3);
                ws += wsel;
            }
        }

        // combine the even/odd-edge halves
        acc0 += __shfl_xor(acc0, 32);
        acc1 += __shfl_xor(acc1, 32);
        acc2 += __shfl_xor(acc2, 32);
        acc3 += __shfl_xor(acc3, 32);
        ws   += __shfl_xor(ws, 32);
        float inv = 1.f / (ws + 1e-16f);
        float vx = h ? acc2 : acc0;
        float vy = h ? acc3 : acc1;
        vx = fmaxf(fmaf(vx, inv, b2.x), 0.f);
        vy = fmaxf(fmaf(vy, inv, b2.y), 0.f);

        if (pool_flag) {
            atomicAdd(&pooled[ba[k] * DIM + p0], vx);
            atomicAdd(&pooled[ba[k] * DIM + p0 + 1], vy);
        } else {
            ushort2 hb;
            hb.x = f2bf(vx);
            hb.y = f2bf(vy);
            ((ushort2*)Xout)[(size_t)(node0 + k) * 64 + (p0 >> 1)] = hb;
        }
    }
}

__global__ void final_kernel(const float* __restrict__ pooled, const float* __restrict__ Wf,
                             const float* __restrict__ bf, float* __restrict__ y) {
    int wid = (blockIdx.x * blockDim.x + threadIdx.x) >> 6;
    int lane = threadIdx.x & 63;
    if (wid >= N_GRAPHS) return;
    float2 p = *(const float2*)&pooled[wid * DIM + 2 * lane];
    int cc = lane >> 2, ii = lane & 3;
    float wx = Wf[cc + 32 * ii];
    float wy = Wf[cc + 32 * ii + 16];
    float v = p.x * wx + p.y * wy;
    for (int off = 32; off; off >>= 1) v += __shfl_down(v, off);
    if (lane == 0) y[wid] = v + bf[0];
}

extern "C" void kernel_launch(void* const* d_in, const int* in_sizes, int n_in,
                              void* d_out, int out_size, void* d_ws, size_t ws_size,
                              hipStream_t stream) {
    const float* x       = (const float*)d_in[0];
    const int*   ei      = (const int*)d_in[1];
    const int*   batch   = (const int*)d_in[2];
    const float* Ws      = (const float*)d_in[3];
    const float* att_src = (const float*)d_in[4];
    const float* att_dst = (const float*)d_in[5];
    const float* biases  = (const float*)d_in[6];
    const float* Wf      = (const float*)d_in[7];
    const float* bf      = (const float*)d_in[8];
    float* y = (float*)d_out;

    char* p = (char*)d_ws;
    auto alloc = [&](size_t bytes) -> void* {
        void* r = (void*)p;
        p += (bytes + 255) & ~(size_t)255;
        return r;
    };
    ushort* xC     = (ushort*)alloc((size_t)(N_NODES + 64) * DIM * 2);  // bf16
    ushort* xA     = (ushort*)alloc((size_t)(N_NODES + 64) * DIM * 2);  // bf16
    uint*   Hb     = (uint*)alloc((size_t)N_NODES * 32 * 4);   // fp8 e4m3, 128 B/row
    ushort* Wfrag  = (ushort*)alloc((size_t)3 * 32 * 64 * 8 * 2);
    uint*  csr     = (uint*)alloc((size_t)E_CAP * 4);          // src|dst<<16 packed
    float* wbuf    = (float*)alloc((size_t)E_CAP * 4);
    int*   deg     = (int*)alloc((size_t)N_NODES * 4);
    int*   fillc   = (int*)alloc((size_t)N_NODES * 4);
    int*   row_ptr = (int*)alloc((size_t)(N_NODES + 16) * 4);
    int*   blksum  = (int*)alloc(256 * 4);
    float* s1      = (float*)alloc((size_t)N_NODES * 4);
    float* s2      = (float*)alloc((size_t)(N_NODES + 8) * 4);
    float* pooled  = (float*)alloc((size_t)N_GRAPHS * DIM * 4);

    const int BN = 256;
    const int gN   = (N_NODES + BN - 1) / BN;
    const int gE   = (E_TOT + BN - 1) / BN;
    const int ngroups = N_NODES / 4;                 // 12500, exact
    const int gAGG = (ngroups * 64 + BN - 1) / BN;   // one wave per 4 nodes
    const int nblk = gN;
    const int gCVT = (N_NODES * DIM / 4 + BN - 1) / BN;
    const int gGEMM = (N_NODES + 63) / 64;
    const int gEW  = (NSLOT / 4 + BN - 1) / BN;
    const int gCI  = (NSLOT / 4 + BN - 1) / BN;

    init_kernel<<<gN, BN, 0, stream>>>(deg, fillc, pooled);
    csr_init_kernel<<<gCI, BN, 0, stream>>>(csr);
    x2bf_kernel<<<gCVT, BN, 0, stream>>>(x, xC);
    wprep_kernel<<<(3 * 32 * 64 + BN - 1) / BN, BN, 0, stream>>>(Ws, Wfrag);
    count_kernel<<<gE, BN, 0, stream>>>(ei, deg);
    scan1_kernel<<<nblk, BN, 0, stream>>>(deg, row_ptr, blksum, N_NODES);
    scan2_kernel<<<1, BN, 0, stream>>>(blksum, row_ptr, nblk);
    scan3_kernel<<<gN, BN, 0, stream>>>(row_ptr, blksum, N_NODES);
    fill_kernel<<<gE, BN, 0, stream>>>(ei, row_ptr, fillc, csr);

    const ushort* xin = xC;
    ushort* xout = xA;
    for (int l = 0; l < 3; ++l) {
        const ushort* Wf_l = Wfrag + (size_t)l * 32 * 64 * 8;
        const float* as = att_src + (size_t)l * DIM;
        const float* ad = att_dst + (size_t)l * DIM;
        const float* b  = biases + (size_t)l * DIM;

        gemm_mfma_kernel<<<gGEMM, BN, 0, stream>>>(xin, Wf_l, as, ad, Hb, s1, s2, N_NODES);
        ew_kernel<<<gEW, BN, 0, stream>>>(csr, s1, s2, wbuf);
        agg_kernel<<<gAGG, BN, 0, stream>>>(Hb, csr, row_ptr, wbuf, b,
                                            xout, batch, pooled,
                                            (l == 2) ? 1 : 0, ngroups);
        xin = xout;
        xout = (l == 0) ? xC : xA;   // ping-pong: xC free after layer-0 GEMM
    }

    final_kernel<<<(N_GRAPHS * 64 + BN - 1) / BN, BN, 0, stream>>>(pooled, Wf, bf, y);
    (void)ws_size; (void)n_in; (void)in_sizes; (void)out_size;
}

// Round 4
// 354.547 us; speedup vs baseline: 1.4071x; 1.4071x over previous
//
#include <hip/hip_runtime.h>
#include <hip/hip_bf16.h>

#define N_NODES 50000
#define DIM 128
#define N_GRAPHS 64
#define E_RAW 800000
#define E_TOT 850000
#define NSLOT 1000000   // E_TOT + 3*N_NODES: exact upper bound on padded slots
#define E_CAP 1200000
#define NEG_SLOPE 0.2f
#define PAD_SENT 0xFFFF0000u   // src field = 0 (safe gather), dst field = 0xFFFF (pad)

typedef unsigned int uint;
typedef unsigned short ushort;
typedef float v2f __attribute__((ext_vector_type(2)));
typedef short bf16x8 __attribute__((ext_vector_type(8)));
typedef float f32x4 __attribute__((ext_vector_type(4)));

// Column permutation pi (storage position -> logical feature), fixed by the
// MFMA C/D fragment layout: pi(p) = (p>>3) + 32*((p>>1)&3) + 16*(p&1)
__device__ __forceinline__ int pi_pos(int p) {
    return (p >> 3) + 32 * ((p >> 1) & 3) + 16 * (p & 1);
}

__device__ __forceinline__ ushort f2bf(float f) {
    uint u = __float_as_uint(f);
    u += 0x7fffu + ((u >> 16) & 1u);      // RNE
    return (ushort)(u >> 16);
}

// ---------- init: counters + pooled only ----------
__global__ void init_kernel(int* deg, int* fillc, float* pooled) {
    int i = blockIdx.x * blockDim.x + threadIdx.x;
    if (i < N_NODES) { deg[i] = 0; fillc[i] = 0; }
    if (i < N_GRAPHS * DIM) pooled[i] = 0.f;
}

// ---------- fill csr[0..NSLOT) with pad sentinel ----------
__global__ void csr_init_kernel(uint* __restrict__ csr) {
    int i = blockIdx.x * blockDim.x + threadIdx.x;
    if (i < NSLOT / 4) ((uint4*)csr)[i] = make_uint4(PAD_SENT, PAD_SENT, PAD_SENT, PAD_SENT);
}

// ---------- layer-0 input fp32 -> bf16 (natural order) ----------
__global__ void x2bf_kernel(const float* __restrict__ x, ushort* __restrict__ xb) {
    int i = blockIdx.x * blockDim.x + threadIdx.x;
    if (i >= N_NODES * DIM / 4) return;
    float4 v = ((const float4*)x)[i];
    ushort4 o;
    o.x = f2bf(v.x); o.y = f2bf(v.y); o.z = f2bf(v.z); o.w = f2bf(v.w);
    ((ushort4*)xb)[i] = o;
}

// ---------- pack W into per-lane MFMA B-fragment layout (bf16) ----------
__global__ void wprep_kernel(const float* __restrict__ Ws, ushort* __restrict__ Wfrag) {
    int t = blockIdx.x * blockDim.x + threadIdx.x;
    if (t >= 3 * 32 * 64) return;
    int l = t >> 11;
    int rem = t & 2047;
    int chunk = rem >> 6, lane = rem & 63;
    int ks = chunk >> 3, nt = chunk & 7;
    int cc = lane & 15, gg = lane >> 4;
    const float* W = Ws + (size_t)l * DIM * DIM;
    ushort o[8];
#pragma unroll
    for (int j = 0; j < 8; ++j) {
        int kp = ks * 32 + gg * 8 + j;
        int kl = (l == 0) ? kp : pi_pos(kp);
        o[j] = f2bf(W[kl * DIM + nt * 16 + cc]);
    }
#pragma unroll
    for (int j = 0; j < 8; ++j) Wfrag[(size_t)t * 8 + j] = o[j];
}

// ---------- CSR build (dst-sorted, segments padded to multiple of 4) ----------
__global__ void count_kernel(const int* __restrict__ ei, int* __restrict__ deg) {
    int e = blockIdx.x * blockDim.x + threadIdx.x;
    if (e >= E_TOT) return;
    int dst = (e < E_RAW) ? ei[E_RAW + e] : (e - E_RAW);
    atomicAdd(&deg[dst], 1);
}

__global__ void scan1_kernel(const int* __restrict__ deg, int* __restrict__ excl,
                             int* __restrict__ blksum, int n) {
    __shared__ int lds[256];
    int t = threadIdx.x;
    int i = blockIdx.x * 256 + t;
    int v = (i < n) ? ((deg[i] + 3) & ~3) : 0;   // pad degree to multiple of 4
    lds[t] = v;
    __syncthreads();
    int incl = v;
    for (int off = 1; off < 256; off <<= 1) {
        int y = (t >= off) ? lds[t - off] : 0;
        __syncthreads();
        incl += y;
        lds[t] = incl;
        __syncthreads();
    }
    if (i < n) excl[i] = incl - v;
    if (t == 255) blksum[blockIdx.x] = incl;
}

__global__ void scan2_kernel(int* __restrict__ blksum, int* __restrict__ row_ptr, int nblk) {
    __shared__ int lds[256];
    int t = threadIdx.x;
    int v = (t < nblk) ? blksum[t] : 0;
    lds[t] = v;
    __syncthreads();
    int incl = v;
    for (int off = 1; off < 256; off <<= 1) {
        int y = (t >= off) ? lds[t - off] : 0;
        __syncthreads();
        incl += y;
        lds[t] = incl;
        __syncthreads();
    }
    if (t < nblk) blksum[t] = incl - v;
    if (t == nblk - 1) row_ptr[N_NODES] = incl;
}

__global__ void scan3_kernel(int* __restrict__ row_ptr, const int* __restrict__ blksum, int n) {
    int i = blockIdx.x * blockDim.x + threadIdx.x;
    if (i < n) row_ptr[i] += blksum[i >> 8];
}

// packed entry: src | (dst<<16). N_NODES < 65536 so both fit.
__global__ void fill_kernel(const int* __restrict__ ei, const int* __restrict__ row_ptr,
                            int* __restrict__ fillc, uint* __restrict__ csr) {
    int e = blockIdx.x * blockDim.x + threadIdx.x;
    if (e >= E_TOT) return;
    int src, dst;
    if (e < E_RAW) { src = ei[e]; dst = ei[E_RAW + e]; }
    else           { src = dst = e - E_RAW; }
    int slot = row_ptr[dst] + atomicAdd(&fillc[dst], 1);
    csr[slot] = (uint)src | ((uint)dst << 16);
}

// ---------- MFMA GEMM + fused attention dots; H packed fp8 e4m3 (pi order) ----
__global__ __launch_bounds__(256) void gemm_mfma_kernel(
    const ushort* __restrict__ Xb, const ushort* __restrict__ Wfrag,
    const float* __restrict__ asrc, const float* __restrict__ adst,
    uint* __restrict__ Hb, float* __restrict__ s1, float* __restrict__ s2, int nrows) {
    int wv = threadIdx.x >> 6;
    int lane = threadIdx.x & 63;
    int c = lane & 15, g = lane >> 4;
    int row0 = blockIdx.x * 64 + wv * 16;

    int arow = row0 + c;
    if (arow >= nrows) arow = nrows - 1;           // tail clamp (writes guarded)
    const ushort* xrow = Xb + (size_t)arow * DIM;

    f32x4 acc[8];
#pragma unroll
    for (int nt = 0; nt < 8; ++nt) acc[nt] = (f32x4)(0.f);

#pragma unroll
    for (int ks = 0; ks < 4; ++ks) {
        bf16x8 afrag = *(const bf16x8*)(xrow + ks * 32 + g * 8);
#pragma unroll
        for (int nt = 0; nt < 8; ++nt) {
            bf16x8 bfrag = *(const bf16x8*)(Wfrag + ((size_t)(ks * 8 + nt) * 64 + lane) * 8);
            acc[nt] = __builtin_amdgcn_mfma_f32_16x16x32_bf16(afrag, bfrag, acc[nt], 0, 0, 0);
        }
    }

    float a1[8], a2[8];
#pragma unroll
    for (int nt = 0; nt < 8; ++nt) { a1[nt] = asrc[c + 16 * nt]; a2[nt] = adst[c + 16 * nt]; }

#pragma unroll
    for (int r = 0; r < 4; ++r) {
        int outrow = row0 + g * 4 + r;
        bool valid = outrow < nrows;
        if (valid) {
            int w0 = __builtin_amdgcn_cvt_pk_fp8_f32(acc[0][r], acc[1][r], 0, false);
            w0     = __builtin_amdgcn_cvt_pk_fp8_f32(acc[2][r], acc[3][r], w0, true);
            int w1 = __builtin_amdgcn_cvt_pk_fp8_f32(acc[4][r], acc[5][r], 0, false);
            w1     = __builtin_amdgcn_cvt_pk_fp8_f32(acc[6][r], acc[7][r], w1, true);
            *(uint2*)&Hb[(size_t)outrow * 32 + c * 2] = make_uint2((uint)w0, (uint)w1);
        }
        float p1 = 0.f, p2 = 0.f;
#pragma unroll
        for (int nt = 0; nt < 8; ++nt) {
            p1 = fmaf(acc[nt][r], a1[nt], p1);
            p2 = fmaf(acc[nt][r], a2[nt], p2);
        }
#pragma unroll
        for (int m = 1; m < 16; m <<= 1) { p1 += __shfl_xor(p1, m); p2 += __shfl_xor(p2, m); }
        if (c == 0 && valid) { s1[outrow] = p1; s2[outrow] = p2; }
    }
}

// ---------- per-edge attention weight, computed ONCE per edge ----------
// packed csr: src = lo16, dst = hi16; pad slots (dst==0xFFFF) get w = 0.
__global__ __launch_bounds__(256) void ew_kernel(
    const uint* __restrict__ csr, const float* __restrict__ s1,
    const float* __restrict__ s2, float* __restrict__ w) {
    int i = blockIdx.x * blockDim.x + threadIdx.x;
    if (i >= NSLOT / 4) return;
    uint4 e = ((const uint4*)csr)[i];
    uint ev[4] = {e.x, e.y, e.z, e.w};
    float ov[4];
#pragma unroll
    for (int j = 0; j < 4; ++j) {
        uint dv = ev[j] >> 16;
        uint sv = ev[j] & 0xFFFFu;
        float wv = 0.f;
        if (dv != 0xFFFFu) {
            float al = s1[sv] + s2[dv];
            al = fmaxf(al, NEG_SLOPE * al);     // leaky-relu
            wv = __expf(al);
        }
        ov[j] = wv;
    }
    float4 o;
    o.x = ov[0]; o.y = ov[1]; o.z = ov[2]; o.w = ov[3];
    ((float4*)w)[i] = o;
}

// ---------- weighted gather-aggregate: one wave per EIGHT dst nodes ----------
// dwordx2 gathers: each instruction covers FOUR edge fp8 rows (16 lanes/row,
// 8 B/lane). Lane group g = lane>>4 handles edge s+g of each 4-edge subchunk;
// each lane accumulates 8 features (storage bytes 8*ql .. 8*ql+7). Groups are
// combined with a shfl_xor(16)/shfl_xor(32) butterfly at segment end.
// NOTE: no readfirstlane, no runtime-indexed local arrays in the hot loop
// (round-3 regression: compiler demoted locals to LDS, 18M bank conflicts).
__global__ __launch_bounds__(256) void agg_kernel(
    const uint2* __restrict__ Hb2, const uint* __restrict__ csr,
    const int* __restrict__ row_ptr, const float* __restrict__ w,
    const float* __restrict__ bias,
    ushort* __restrict__ Xout, const int* __restrict__ batch,
    float* __restrict__ pooled, int pool_flag, int ngroups) {
    int gw = (blockIdx.x * blockDim.x + threadIdx.x) >> 6;
    int lane = threadIdx.x & 63;
    if (gw >= ngroups) return;
    int node0 = gw * 8;
    int ql = lane & 15;         // uint2 (8-feature) index within fp8 row
    int grp = lane >> 4;        // 0..3: which edge of each 4-edge subchunk

    int4 rpa = *(const int4*)&row_ptr[node0];
    int4 rpb = *(const int4*)&row_ptr[node0 + 4];
    int rp8 = row_ptr[node0 + 8];
    int rp[9] = {rpa.x, rpa.y, rpa.z, rpa.w, rpb.x, rpb.y, rpb.z, rpb.w, rp8};

    int p0 = 8 * ql + 2 * grp;  // pi-storage position this lane writes (even)
    float2 b2;
    b2.x = bias[pi_pos(p0)];
    b2.y = bias[pi_pos(p0) + 16];

    int ba[8] = {0, 0, 0, 0, 0, 0, 0, 0};
    if (pool_flag) {
        int4 bqa = *(const int4*)&batch[node0];
        int4 bqb = *(const int4*)&batch[node0 + 4];
        ba[0] = bqa.x; ba[1] = bqa.y; ba[2] = bqa.z; ba[3] = bqa.w;
        ba[4] = bqb.x; ba[5] = bqb.y; ba[6] = bqb.z; ba[7] = bqb.w;
    }

#pragma unroll
    for (int k = 0; k < 8; ++k) {
        int beg = rp[k], end = rp[k + 1];
        float a0 = 0.f, a1 = 0.f, a2 = 0.f, a3 = 0.f;
        float a4 = 0.f, a5 = 0.f, a6 = 0.f, a7 = 0.f, ws = 0.f;

        for (int s = beg; s < end; s += 8) {
            uint4 ca = *(const uint4*)&csr[s];
            float4 wa = *(const float4*)&w[s];
            bool vb = (s + 4) < end;                     // wave-uniform
            uint4 cb = vb ? *(const uint4*)&csr[s + 4]
                          : make_uint4(PAD_SENT, PAD_SENT, PAD_SENT, PAD_SENT);
            float4 wb = vb ? *(const float4*)&w[s + 4] : make_float4(0.f, 0.f, 0.f, 0.f);

            uint  eA = (grp == 0) ? ca.x : (grp == 1) ? ca.y : (grp == 2) ? ca.z : ca.w;
            float wA = (grp == 0) ? wa.x : (grp == 1) ? wa.y : (grp == 2) ? wa.z : wa.w;
            uint  eB = (grp == 0) ? cb.x : (grp == 1) ? cb.y : (grp == 2) ? cb.z : cb.w;
            float wB = (grp == 0) ? wb.x : (grp == 1) ? wb.y : (grp == 2) ? wb.z : wb.w;

            uint2 hA = Hb2[(eA & 0xFFFFu) * 16u + (uint)ql];
            uint2 hB = Hb2[(eB & 0xFFFFu) * 16u + (uint)ql];

            v2f f;
            f = __builtin_amdgcn_cvt_pk_f32_fp8((int)hA.x, false); a0 = fmaf(wA, f.x, a0); a1 = fmaf(wA, f.y, a1);
            f = __builtin_amdgcn_cvt_pk_f32_fp8((int)hA.x, true);  a2 = fmaf(wA, f.x, a2); a3 = fmaf(wA, f.y, a3);
            f = __builtin_amdgcn_cvt_pk_f32_fp8((int)hA.y, false); a4 = fmaf(wA, f.x, a4); a5 = fmaf(wA, f.y, a5);
            f = __builtin_amdgcn_cvt_pk_f32_fp8((int)hA.y, true);  a6 = fmaf(wA, f.x, a6); a7 = fmaf(wA, f.y, a7);
            ws += wA;
            f = __builtin_amdgcn_cvt_pk_f32_fp8((int)hB.x, false); a0 = fmaf(wB, f.x, a0); a1 = fmaf(wB, f.y, a1);
            f = __builtin_amdgcn_cvt_pk_f32_fp8((int)hB.x, true);  a2 = fmaf(wB, f.x, a2); a3 = fmaf(wB, f.y, a3);
            f = __builtin_amdgcn_cvt_pk_f32_fp8((int)hB.y, false); a4 = fmaf(wB, f.x, a4); a5 = fmaf(wB, f.y, a5);
            f = __builtin_amdgcn_cvt_pk_f32_fp8((int)hB.y, true);  a6 = fmaf(wB, f.x, a6); a7 = fmaf(wB, f.y, a7);
            ws += wB;
        }

        // combine the 4 lane-groups (each held 1/4 of the edges)
        a0 += __shfl_xor(a0, 16); a0 += __shfl_xor(a0, 32);
        a1 += __shfl_xor(a1, 16); a1 += __shfl_xor(a1, 32);
        a2 += __shfl_xor(a2, 16); a2 += __shfl_xor(a2, 32);
        a3 += __shfl_xor(a3, 16); a3 += __shfl_xor(a3, 32);
        a4 += __shfl_xor(a4, 16); a4 += __shfl_xor(a4, 32);
        a5 += __shfl_xor(a5, 16); a5 += __shfl_xor(a5, 32);
        a6 += __shfl_xor(a6, 16); a6 += __shfl_xor(a6, 32);
        a7 += __shfl_xor(a7, 16); a7 += __shfl_xor(a7, 32);
        ws += __shfl_xor(ws, 16); ws += __shfl_xor(ws, 32);

        float inv = 1.f / (ws + 1e-16f);
        float vx = (grp == 0) ? a0 : (grp == 1) ? a2 : (grp == 2) ? a4 : a6;
        float vy = (grp == 0) ? a1 : (grp == 1) ? a3 : (grp == 2) ? a5 : a7;
        vx = fmaxf(fmaf(vx, inv, b2.x), 0.f);
        vy = fmaxf(fmaf(vy, inv, b2.y), 0.f);

        if (pool_flag) {
            atomicAdd(&pooled[ba[k] * DIM + p0], vx);
            atomicAdd(&pooled[ba[k] * DIM + p0 + 1], vy);
        } else {
            ushort2 hb;
            hb.x = f2bf(vx);
            hb.y = f2bf(vy);
            ((ushort2*)Xout)[(size_t)(node0 + k) * 64 + (p0 >> 1)] = hb;
        }
    }
}

__global__ void final_kernel(const float* __restrict__ pooled, const float* __restrict__ Wf,
                             const float* __restrict__ bf, float* __restrict__ y) {
    int wid = (blockIdx.x * blockDim.x + threadIdx.x) >> 6;
    int lane = threadIdx.x & 63;
    if (wid >= N_GRAPHS) return;
    float2 p = *(const float2*)&pooled[wid * DIM + 2 * lane];
    int cc = lane >> 2, ii = lane & 3;
    float wx = Wf[cc + 32 * ii];
    float wy = Wf[cc + 32 * ii + 16];
    float v = p.x * wx + p.y * wy;
    for (int off = 32; off; off >>= 1) v += __shfl_down(v, off);
    if (lane == 0) y[wid] = v + bf[0];
}

extern "C" void kernel_launch(void* const* d_in, const int* in_sizes, int n_in,
                              void* d_out, int out_size, void* d_ws, size_t ws_size,
                              hipStream_t stream) {
    const float* x       = (const float*)d_in[0];
    const int*   ei      = (const int*)d_in[1];
    const int*   batch   = (const int*)d_in[2];
    const float* Ws      = (const float*)d_in[3];
    const float* att_src = (const float*)d_in[4];
    const float* att_dst = (const float*)d_in[5];
    const float* biases  = (const float*)d_in[6];
    const float* Wf      = (const float*)d_in[7];
    const float* bf      = (const float*)d_in[8];
    float* y = (float*)d_out;

    char* p = (char*)d_ws;
    auto alloc = [&](size_t bytes) -> void* {
        void* r = (void*)p;
        p += (bytes + 255) & ~(size_t)255;
        return r;
    };
    ushort* xC     = (ushort*)alloc((size_t)(N_NODES + 64) * DIM * 2);  // bf16
    ushort* xA     = (ushort*)alloc((size_t)(N_NODES + 64) * DIM * 2);  // bf16
    uint*   Hb     = (uint*)alloc((size_t)N_NODES * 32 * 4);   // fp8 e4m3, 128 B/row
    ushort* Wfrag  = (ushort*)alloc((size_t)3 * 32 * 64 * 8 * 2);
    uint*  csr     = (uint*)alloc((size_t)E_CAP * 4);          // src|dst<<16 packed
    float* wbuf    = (float*)alloc((size_t)E_CAP * 4);
    int*   deg     = (int*)alloc((size_t)N_NODES * 4);
    int*   fillc   = (int*)alloc((size_t)N_NODES * 4);
    int*   row_ptr = (int*)alloc((size_t)(N_NODES + 16) * 4);
    int*   blksum  = (int*)alloc(256 * 4);
    float* s1      = (float*)alloc((size_t)N_NODES * 4);
    float* s2      = (float*)alloc((size_t)(N_NODES + 8) * 4);
    float* pooled  = (float*)alloc((size_t)N_GRAPHS * DIM * 4);

    const int BN = 256;
    const int gN   = (N_NODES + BN - 1) / BN;
    const int gE   = (E_TOT + BN - 1) / BN;
    const int ngroups = N_NODES / 8;                 // 6250, exact
    const int gAGG = (ngroups * 64 + BN - 1) / BN;   // one wave per 8 nodes
    const int nblk = gN;
    const int gCVT = (N_NODES * DIM / 4 + BN - 1) / BN;
    const int gGEMM = (N_NODES + 63) / 64;
    const int gEW  = (NSLOT / 4 + BN - 1) / BN;
    const int gCI  = (NSLOT / 4 + BN - 1) / BN;

    init_kernel<<<gN, BN, 0, stream>>>(deg, fillc, pooled);
    csr_init_kernel<<<gCI, BN, 0, stream>>>(csr);
    x2bf_kernel<<<gCVT, BN, 0, stream>>>(x, xC);
    wprep_kernel<<<(3 * 32 * 64 + BN - 1) / BN, BN, 0, stream>>>(Ws, Wfrag);
    count_kernel<<<gE, BN, 0, stream>>>(ei, deg);
    scan1_kernel<<<nblk, BN, 0, stream>>>(deg, row_ptr, blksum, N_NODES);
    scan2_kernel<<<1, BN, 0, stream>>>(blksum, row_ptr, nblk);
    scan3_kernel<<<gN, BN, 0, stream>>>(row_ptr, blksum, N_NODES);
    fill_kernel<<<gE, BN, 0, stream>>>(ei, row_ptr, fillc, csr);

    const ushort* xin = xC;
    ushort* xout = xA;
    for (int l = 0; l < 3; ++l) {
        const ushort* Wf_l = Wfrag + (size_t)l * 32 * 64 * 8;
        const float* as = att_src + (size_t)l * DIM;
        const float* ad = att_dst + (size_t)l * DIM;
        const float* b  = biases + (size_t)l * DIM;

        gemm_mfma_kernel<<<gGEMM, BN, 0, stream>>>(xin, Wf_l, as, ad, Hb, s1, s2, N_NODES);
        ew_kernel<<<gEW, BN, 0, stream>>>(csr, s1, s2, wbuf);
        agg_kernel<<<gAGG, BN, 0, stream>>>((const uint2*)Hb, csr, row_ptr, wbuf, b,
                                            xout, batch, pooled,
                                            (l == 2) ? 1 : 0, ngroups);
        xin = xout;
        xout = (l == 0) ? xC : xA;   // ping-pong: xC free after layer-0 GEMM
    }

    final_kernel<<<(N_GRAPHS * 64 + BN - 1) / BN, BN, 0, stream>>>(pooled, Wf, bf, y);
    (void)ws_size; (void)n_in; (void)in_sizes; (void)out_size;
}